// Round 2
// baseline (282.294 us; speedup 1.0000x reference)
//
#include <hip/hip_runtime.h>
#include <math.h>

// SSIM loss, fused separable 11x11 Gaussian + SSIM map + mean.
// v2: LDS-op minimization. No input staging (global float4 reads, L1-cached),
// LDS holds only the 5 horizontal-stat planes, all LDS traffic is b128.
// Inputs: img1, img2 float32 [16,3,512,512]. Output: scalar float32.

#define TS_X   64
#define TS_Y   32
#define HALO   5
#define KSZ    11
#define LT_Y   (TS_Y + 2*HALO)   // 42 rows of horizontal stats
#define IMG    512
#define NPLANES 48
#define NPIX   (48*512*512)

__device__ __forceinline__ void get_weights(float* w) {
    float s = 0.f;
#pragma unroll
    for (int i = 0; i < KSZ; ++i) {
        float d = (float)(i - HALO);
        w[i] = expf(-(d * d) / (2.0f * 1.5f * 1.5f));
        s += w[i];
    }
    float inv = 1.0f / s;
#pragma unroll
    for (int i = 0; i < KSZ; ++i) w[i] *= inv;
}

__device__ __forceinline__ void load4g(const float* __restrict__ row, int gx,
                                       float* dst) {
    if (gx >= 0 && gx + 3 < IMG) {
        float4 v = *reinterpret_cast<const float4*>(row + gx);
        dst[0] = v.x; dst[1] = v.y; dst[2] = v.z; dst[3] = v.w;
    } else {
#pragma unroll
        for (int j = 0; j < 4; ++j)
            dst[j] = ((unsigned)(gx + j) < (unsigned)IMG) ? row[gx + j] : 0.f;
    }
}

__global__ void __launch_bounds__(256)
ssim_kernel(const float* __restrict__ img1,
            const float* __restrict__ img2,
            float* __restrict__ acc)
{
    // horizontal-pass stats: mu1, mu2, x1x1, x2x2, x1x2
    __shared__ __align__(16) float h[5][LT_Y][TS_X];   // 52.5 KiB
    __shared__ float wsum[4];

    float w[KSZ];
    get_weights(w);

    const int tid   = threadIdx.x;
    const int bx    = blockIdx.x;
    const int by    = blockIdx.y;
    const int plane = blockIdx.z;

    const float* __restrict__ p1 = img1 + (size_t)plane * IMG * IMG;
    const float* __restrict__ p2 = img2 + (size_t)plane * IMG * IMG;

    // ---------- Phase A: horizontal 11-tap, 4 output cols per item ----------
    // item = (row r in 0..41, col-group g in 0..15). Output cols cbase..cbase+3
    // need input cols cbase-5 .. cbase+8 (global), loaded as 5 aligned float4
    // starting at cbase-8 (20 floats, use [3..16]).
    for (int i = tid; i < LT_Y * 16; i += 256) {
        const int r     = i >> 4;
        const int g     = i & 15;
        const int cbase = g * 4;
        const int gy    = by * TS_Y - HALO + r;

        float in1[20], in2[20];
        if ((unsigned)gy < (unsigned)IMG) {
            const float* row1 = p1 + (size_t)gy * IMG;
            const float* row2 = p2 + (size_t)gy * IMG;
            const int gx0 = bx * TS_X + cbase - 8;
#pragma unroll
            for (int b = 0; b < 5; ++b) {
                load4g(row1, gx0 + b * 4, &in1[b * 4]);
                load4g(row2, gx0 + b * 4, &in2[b * 4]);
            }
        } else {
#pragma unroll
            for (int t = 0; t < 20; ++t) { in1[t] = 0.f; in2[t] = 0.f; }
        }

        // per-column products, computed once (indices 3..16)
        float s11[14], s22[14], s12[14];
#pragma unroll
        for (int t = 0; t < 14; ++t) {
            float a = in1[t + 3], b = in2[t + 3];
            s11[t] = a * a;
            s22[t] = b * b;
            s12[t] = a * b;
        }

        float m1v[4], m2v[4], a11v[4], a22v[4], a12v[4];
#pragma unroll
        for (int q = 0; q < 4; ++q) {
            float m1 = 0.f, m2 = 0.f, a11 = 0.f, a22 = 0.f, a12 = 0.f;
#pragma unroll
            for (int k = 0; k < KSZ; ++k) {
                float wk = w[k];
                m1  += wk * in1[3 + q + k];
                m2  += wk * in2[3 + q + k];
                a11 += wk * s11[q + k];
                a22 += wk * s22[q + k];
                a12 += wk * s12[q + k];
            }
            m1v[q] = m1; m2v[q] = m2; a11v[q] = a11; a22v[q] = a22; a12v[q] = a12;
        }
        *reinterpret_cast<float4*>(&h[0][r][cbase]) = make_float4(m1v[0],  m1v[1],  m1v[2],  m1v[3]);
        *reinterpret_cast<float4*>(&h[1][r][cbase]) = make_float4(m2v[0],  m2v[1],  m2v[2],  m2v[3]);
        *reinterpret_cast<float4*>(&h[2][r][cbase]) = make_float4(a11v[0], a11v[1], a11v[2], a11v[3]);
        *reinterpret_cast<float4*>(&h[3][r][cbase]) = make_float4(a22v[0], a22v[1], a22v[2], a22v[3]);
        *reinterpret_cast<float4*>(&h[4][r][cbase]) = make_float4(a12v[0], a12v[1], a12v[2], a12v[3]);
    }
    __syncthreads();

    // ---------- Phase B: vertical 11-tap + SSIM, 4x4 px per item ----------
    const float C1 = 0.01f * 0.01f;
    const float C2 = 0.03f * 0.03f;
    float local = 0.f;

    if (tid < 128) {
        const int rg = tid >> 4;    // 0..7  -> output rows rg*4 .. rg*4+3
        const int cg = tid & 15;    // 0..15 -> output cols cg*4 .. cg*4+3
        const int r0 = rg * 4;
        const int c4 = cg * 4;

        float ac[4][5][4];          // [out-row][stat][col], fully unrolled
#pragma unroll
        for (int q = 0; q < 4; ++q)
#pragma unroll
            for (int s = 0; s < 5; ++s)
#pragma unroll
                for (int c = 0; c < 4; ++c) ac[q][s][c] = 0.f;

#pragma unroll
        for (int rr = 0; rr < 14; ++rr) {
            float4 hv[5];
#pragma unroll
            for (int s = 0; s < 5; ++s)
                hv[s] = *reinterpret_cast<const float4*>(&h[s][r0 + rr][c4]);
#pragma unroll
            for (int q = 0; q < 4; ++q) {
                if (rr - q >= 0 && rr - q <= 10) {   // compile-time after unroll
                    const float wk = w[rr - q];
#pragma unroll
                    for (int s = 0; s < 5; ++s) {
                        ac[q][s][0] += wk * hv[s].x;
                        ac[q][s][1] += wk * hv[s].y;
                        ac[q][s][2] += wk * hv[s].z;
                        ac[q][s][3] += wk * hv[s].w;
                    }
                }
            }
        }

#pragma unroll
        for (int q = 0; q < 4; ++q) {
#pragma unroll
            for (int c = 0; c < 4; ++c) {
                float mu1 = ac[q][0][c], mu2 = ac[q][1][c];
                float v11 = ac[q][2][c], v22 = ac[q][3][c], v12 = ac[q][4][c];
                float mu1sq = mu1 * mu1;
                float mu2sq = mu2 * mu2;
                float mu12  = mu1 * mu2;
                float sig1  = v11 - mu1sq;
                float sig2  = v22 - mu2sq;
                float sig12 = v12 - mu12;
                float num = (2.f * mu12 + C1) * (2.f * sig12 + C2);
                float den = (mu1sq + mu2sq + C1) * (sig1 + sig2 + C2);
                local += num / den;
            }
        }
    }

    // ---------- block reduction ----------
#pragma unroll
    for (int off = 32; off > 0; off >>= 1)
        local += __shfl_down(local, off, 64);
    if ((tid & 63) == 0) wsum[tid >> 6] = local;
    __syncthreads();
    if (tid == 0) {
        float t = wsum[0] + wsum[1] + wsum[2] + wsum[3];
        atomicAdd(acc, t);
    }
}

__global__ void zero_acc_kernel(float* acc) {
    if (threadIdx.x == 0) acc[0] = 0.f;
}

__global__ void finalize_kernel(const float* __restrict__ acc,
                                float* __restrict__ out) {
    if (threadIdx.x == 0)
        out[0] = 1.0f - acc[0] * (1.0f / (float)NPIX);
}

extern "C" void kernel_launch(void* const* d_in, const int* in_sizes, int n_in,
                              void* d_out, int out_size, void* d_ws, size_t ws_size,
                              hipStream_t stream) {
    const float* img1 = (const float*)d_in[0];
    const float* img2 = (const float*)d_in[1];
    float* out = (float*)d_out;
    float* acc = (float*)d_ws;

    zero_acc_kernel<<<1, 64, 0, stream>>>(acc);
    dim3 grid(IMG / TS_X, IMG / TS_Y, NPLANES);
    ssim_kernel<<<grid, 256, 0, stream>>>(img1, img2, acc);
    finalize_kernel<<<1, 64, 0, stream>>>(acc, out);
}